// Round 1
// baseline (3335.660 us; speedup 1.0000x reference)
//
#include <hip/hip_runtime.h>

#define N_USERS_C 100000
#define N_OUTFITS_C 100000
#define N_NODES_C 200000
#define EMBED_C 128
#define LAYERS_C 3
#define NEG_SLOPE_C 0.01f
#define EPS_C 1e-12f

// ---------------------------------------------------------------- init
__global__ __launch_bounds__(256) void init_ego_out(
    const float* __restrict__ user_emb, const int* __restrict__ u_id,
    const float* __restrict__ o_emb, float* __restrict__ ego,
    float* __restrict__ out) {
  int i4 = blockIdx.x * blockDim.x + threadIdx.x;  // float4 index
  if (i4 >= N_NODES_C * (EMBED_C / 4)) return;
  int r = i4 >> 5;   // row (EMBED/4 == 32)
  int c4 = i4 & 31;
  float4 v;
  if (r < N_USERS_C) {
    int src = u_id[r];
    v = reinterpret_cast<const float4*>(user_emb)[(size_t)src * 32 + c4];
  } else {
    v = reinterpret_cast<const float4*>(o_emb)[(size_t)(r - N_USERS_C) * 32 + c4];
  }
  reinterpret_cast<float4*>(ego)[i4] = v;
  reinterpret_cast<float4*>(out)[i4] = v;
}

// ---------------------------------------------------------------- CSR build
__global__ __launch_bounds__(256) void count_edges(
    const int* __restrict__ erow, int* __restrict__ counts, int nnz) {
  int e = blockIdx.x * blockDim.x + threadIdx.x;
  if (e < nnz) atomicAdd(&counts[erow[e]], 1);
}

__global__ __launch_bounds__(256) void scan_a(
    const int* __restrict__ counts, int* __restrict__ row_ptr,
    int* __restrict__ bsums, int n) {
  __shared__ int tmp[256];
  int t = threadIdx.x;
  int idx = blockIdx.x * 256 + t;
  int v = (idx < n) ? counts[idx] : 0;
  tmp[t] = v;
  __syncthreads();
  for (int off = 1; off < 256; off <<= 1) {
    int a = tmp[t];
    if (t >= off) a += tmp[t - off];
    __syncthreads();
    tmp[t] = a;
    __syncthreads();
  }
  if (idx < n) row_ptr[idx + 1] = tmp[t];
  if (t == 255) bsums[blockIdx.x] = tmp[t];
}

__global__ __launch_bounds__(1024) void scan_b(int* __restrict__ bsums, int nb) {
  __shared__ int tmp[1024];
  int t = threadIdx.x;
  int v = (t < nb) ? bsums[t] : 0;
  tmp[t] = v;
  __syncthreads();
  for (int off = 1; off < 1024; off <<= 1) {
    int a = tmp[t];
    if (t >= off) a += tmp[t - off];
    __syncthreads();
    tmp[t] = a;
    __syncthreads();
  }
  if (t < nb) bsums[t] = tmp[t];
}

__global__ __launch_bounds__(256) void scan_c(
    const int* __restrict__ counts, int* __restrict__ row_ptr,
    const int* __restrict__ bsums, int* __restrict__ cursor, int n) {
  int b = blockIdx.x;
  int idx = b * 256 + threadIdx.x;
  if (idx >= n) return;
  int off = (b > 0) ? bsums[b - 1] : 0;
  int incl = row_ptr[idx + 1] + off;
  row_ptr[idx + 1] = incl;
  cursor[idx] = incl - counts[idx];
  if (idx == 0) row_ptr[0] = 0;
}

__global__ __launch_bounds__(256) void scatter_edges(
    const int* __restrict__ erow, const int* __restrict__ ecol,
    const float* __restrict__ eval, int* __restrict__ cursor,
    int* __restrict__ scol, float* __restrict__ sval, int nnz) {
  int e = blockIdx.x * blockDim.x + threadIdx.x;
  if (e >= nnz) return;
  int r = erow[e];
  int pos = atomicAdd(&cursor[r], 1);
  scol[pos] = ecol[e];
  sval[pos] = eval[e];
}

// ---------------------------------------------------------------- SpMM (CSR, one wave per row)
__global__ __launch_bounds__(256) void spmm_csr(
    const int* __restrict__ row_ptr, const int* __restrict__ scol,
    const float* __restrict__ sval, const float* __restrict__ ego,
    float* __restrict__ side) {
  int row = blockIdx.x * 4 + (threadIdx.x >> 6);
  int lane = threadIdx.x & 63;
  if (row >= N_NODES_C) return;
  int s = row_ptr[row], e = row_ptr[row + 1];
  const float2* eg = reinterpret_cast<const float2*>(ego);
  float ax = 0.f, ay = 0.f;
  for (int base = s; base < e; base += 64) {
    int n = e - base;
    if (n > 64) n = 64;
    int c = 0;
    float v = 0.f;
    if (lane < n) {
      c = scol[base + lane];
      v = sval[base + lane];
    }
    for (int tt = 0; tt < n; ++tt) {
      int ct = __shfl(c, tt);
      float vt = __shfl(v, tt);
      float2 g = eg[(size_t)ct * 64 + lane];
      ax = fmaf(vt, g.x, ax);
      ay = fmaf(vt, g.y, ay);
    }
  }
  float2 o;
  o.x = ax;
  o.y = ay;
  reinterpret_cast<float2*>(side)[(size_t)row * 64 + lane] = o;
}

// ---------------------------------------------------------------- fused dense layer
// y = W1*side + b1 + W2*(ego*side) + b2 ; ego' = leaky(y) ; out += ego'/||ego'||
__global__ __launch_bounds__(256) void dense_layer(
    const float* __restrict__ side, float* __restrict__ ego,
    const float* __restrict__ w1, const float* __restrict__ b1,
    const float* __restrict__ w2, const float* __restrict__ b2,
    float* __restrict__ out) {
  __shared__ float s_lds[16][128];
  __shared__ float p_lds[16][128];
  __shared__ float red[4][8];
  int t = threadIdx.x;
  int nb = blockIdx.x * 16;
  // stage side and prod tiles (coalesced float4)
  for (int r = 0; r < 2; ++r) {
    int i = t + r * 256;
    int m = i >> 5;
    int k4 = i & 31;
    size_t gidx = ((size_t)(nb + m)) * 32 + k4;
    float4 sv = reinterpret_cast<const float4*>(side)[gidx];
    float4 ev = reinterpret_cast<const float4*>(ego)[gidx];
    *reinterpret_cast<float4*>(&s_lds[m][k4 * 4]) = sv;
    float4 pv;
    pv.x = sv.x * ev.x;
    pv.y = sv.y * ev.y;
    pv.z = sv.z * ev.z;
    pv.w = sv.w * ev.w;
    *reinterpret_cast<float4*>(&p_lds[m][k4 * 4]) = pv;
  }
  __syncthreads();
  int j = t & 127;
  int g = t >> 7;
  int mb = g * 8;
  float acc[8];
  float binit = b1[j] + b2[j];
#pragma unroll
  for (int m = 0; m < 8; ++m) acc[m] = binit;
  const float* w1r = w1 + j * 128;
  const float* w2r = w2 + j * 128;
#pragma unroll 4
  for (int k0 = 0; k0 < 128; k0 += 4) {
    float4 wv = *reinterpret_cast<const float4*>(w1r + k0);
#pragma unroll
    for (int m = 0; m < 8; ++m) {
      float4 sv = *reinterpret_cast<const float4*>(&s_lds[mb + m][k0]);
      acc[m] += wv.x * sv.x + wv.y * sv.y + wv.z * sv.z + wv.w * sv.w;
    }
  }
#pragma unroll 4
  for (int k0 = 0; k0 < 128; k0 += 4) {
    float4 wv = *reinterpret_cast<const float4*>(w2r + k0);
#pragma unroll
    for (int m = 0; m < 8; ++m) {
      float4 pv = *reinterpret_cast<const float4*>(&p_lds[mb + m][k0]);
      acc[m] += wv.x * pv.x + wv.y * pv.y + wv.z * pv.z + wv.w * pv.w;
    }
  }
  float y[8];
#pragma unroll
  for (int m = 0; m < 8; ++m) {
    float a = acc[m];
    y[m] = (a >= 0.f) ? a : NEG_SLOPE_C * a;
  }
  int wave = t >> 6;
#pragma unroll
  for (int m = 0; m < 8; ++m) {
    float v = y[m] * y[m];
    for (int off = 32; off > 0; off >>= 1) v += __shfl_xor(v, off);
    if ((t & 63) == 0) red[wave][m] = v;
  }
  __syncthreads();
#pragma unroll
  for (int m = 0; m < 8; ++m) {
    float tot = red[g * 2][m] + red[g * 2 + 1][m];
    float scale = 1.0f / fmaxf(sqrtf(tot), EPS_C);
    size_t idx = ((size_t)(nb + mb + m)) * 128 + j;
    ego[idx] = y[m];
    out[idx] += y[m] * scale;
  }
}

// ---------------------------------------------------------------- launch
extern "C" void kernel_launch(void* const* d_in, const int* in_sizes, int n_in,
                              void* d_out, int out_size, void* d_ws,
                              size_t ws_size, hipStream_t stream) {
  const int* erow = (const int*)d_in[0];
  const int* ecol = (const int*)d_in[1];
  const float* eval = (const float*)d_in[2];
  const float* o_emb = (const float*)d_in[3];
  const int* u_id = (const int*)d_in[4];
  const float* user_emb = (const float*)d_in[5];
  const float* fc1_w = (const float*)d_in[6];
  const float* fc1_b = (const float*)d_in[7];
  const float* fc2_w = (const float*)d_in[8];
  const float* fc2_b = (const float*)d_in[9];
  float* out = (float*)d_out;
  int nnz = in_sizes[0];

  char* ws = (char*)d_ws;
  size_t off = 0;
  auto alloc = [&](size_t bytes) {
    void* p = ws + off;
    off += (bytes + 255) & ~(size_t)255;
    return p;
  };
  float* ego = (float*)alloc((size_t)N_NODES_C * EMBED_C * 4);
  float* side = (float*)alloc((size_t)N_NODES_C * EMBED_C * 4);
  int* scol = (int*)alloc((size_t)nnz * 4);
  float* sval = (float*)alloc((size_t)nnz * 4);
  int* row_ptr = (int*)alloc((size_t)(N_NODES_C + 1) * 4);
  int* counts = (int*)alloc((size_t)N_NODES_C * 4);
  int* cursor = (int*)alloc((size_t)N_NODES_C * 4);
  int* bsums = (int*)alloc(4096);

  hipMemsetAsync(counts, 0, (size_t)N_NODES_C * 4, stream);
  init_ego_out<<<(N_NODES_C * 32 + 255) / 256, 256, 0, stream>>>(
      user_emb, u_id, o_emb, ego, out);
  count_edges<<<(nnz + 255) / 256, 256, 0, stream>>>(erow, counts, nnz);
  int nbs = (N_NODES_C + 255) / 256;
  scan_a<<<nbs, 256, 0, stream>>>(counts, row_ptr, bsums, N_NODES_C);
  scan_b<<<1, 1024, 0, stream>>>(bsums, nbs);
  scan_c<<<nbs, 256, 0, stream>>>(counts, row_ptr, bsums, cursor, N_NODES_C);
  scatter_edges<<<(nnz + 255) / 256, 256, 0, stream>>>(erow, ecol, eval, cursor,
                                                       scol, sval, nnz);
  for (int l = 0; l < LAYERS_C; ++l) {
    spmm_csr<<<(N_NODES_C + 3) / 4, 256, 0, stream>>>(row_ptr, scol, sval, ego,
                                                      side);
    dense_layer<<<N_NODES_C / 16, 256, 0, stream>>>(
        side, ego, fc1_w + l * EMBED_C * EMBED_C, fc1_b + l * EMBED_C,
        fc2_w + l * EMBED_C * EMBED_C, fc2_b + l * EMBED_C, out);
  }
}

// Round 2
// 2558.502 us; speedup vs baseline: 1.3038x; 1.3038x over previous
//
#include <hip/hip_runtime.h>

#define N_USERS_C 100000
#define N_OUTFITS_C 100000
#define N_NODES_C 200000
#define EMBED_C 128
#define LAYERS_C 3
#define NEG_SLOPE_C 0.01f
#define EPS_C 1e-12f

typedef float f32x4 __attribute__((ext_vector_type(4)));
typedef short s16x8 __attribute__((ext_vector_type(8)));
typedef __bf16 bf16x8 __attribute__((ext_vector_type(8)));

// ---- MFMA shim: works whether the builtin wants short8 or bf16x8 ----
template <typename T>
__device__ inline auto mfma_bf16_(T a, T b, f32x4 c, int)
    -> decltype(__builtin_amdgcn_mfma_f32_16x16x32_bf16(a, b, c, 0, 0, 0)) {
  return __builtin_amdgcn_mfma_f32_16x16x32_bf16(a, b, c, 0, 0, 0);
}
template <typename T>
__device__ inline f32x4 mfma_bf16_(T a, T b, f32x4 c, long) {
  union U { T s; bf16x8 b; };
  U ua; ua.s = a;
  U ub; ub.s = b;
  return __builtin_amdgcn_mfma_f32_16x16x32_bf16(ua.b, ub.b, c, 0, 0, 0);
}
__device__ inline f32x4 MFMA16(s16x8 a, s16x8 b, f32x4 c) {
  return mfma_bf16_(a, b, c, 0);
}

// ---- bf16 helpers (manual RNE; no header API dependency) ----
__device__ inline unsigned short f2bf(float x) {
  unsigned u = __builtin_bit_cast(unsigned, x);
  u = (u + 0x7fffu + ((u >> 16) & 1u)) >> 16;
  return (unsigned short)u;
}
__device__ inline float bf2f(unsigned short h) {
  unsigned u = ((unsigned)h) << 16;
  return __builtin_bit_cast(float, u);
}

// ---------------------------------------------------------------- init
__global__ __launch_bounds__(256) void init_ego_out(
    const float* __restrict__ user_emb, const int* __restrict__ u_id,
    const float* __restrict__ o_emb, float* __restrict__ ego,
    float* __restrict__ out) {
  int i4 = blockIdx.x * blockDim.x + threadIdx.x;  // float4 index
  if (i4 >= N_NODES_C * (EMBED_C / 4)) return;
  int r = i4 >> 5;  // row (EMBED/4 == 32)
  int c4 = i4 & 31;
  float4 v;
  if (r < N_USERS_C) {
    int src = u_id[r];
    v = reinterpret_cast<const float4*>(user_emb)[(size_t)src * 32 + c4];
  } else {
    v = reinterpret_cast<const float4*>(o_emb)[(size_t)(r - N_USERS_C) * 32 + c4];
  }
  reinterpret_cast<float4*>(ego)[i4] = v;
  reinterpret_cast<float4*>(out)[i4] = v;
}

// ---------------------------------------------------------------- CSR build
__global__ __launch_bounds__(256) void count_edges(
    const int* __restrict__ erow, int* __restrict__ counts, int nnz) {
  int e = blockIdx.x * blockDim.x + threadIdx.x;
  if (e < nnz) atomicAdd(&counts[erow[e]], 1);
}

__global__ __launch_bounds__(256) void scan_a(
    const int* __restrict__ counts, int* __restrict__ row_ptr,
    int* __restrict__ bsums, int n) {
  __shared__ int tmp[256];
  int t = threadIdx.x;
  int idx = blockIdx.x * 256 + t;
  int v = (idx < n) ? counts[idx] : 0;
  tmp[t] = v;
  __syncthreads();
  for (int off = 1; off < 256; off <<= 1) {
    int a = tmp[t];
    if (t >= off) a += tmp[t - off];
    __syncthreads();
    tmp[t] = a;
    __syncthreads();
  }
  if (idx < n) row_ptr[idx + 1] = tmp[t];
  if (t == 255) bsums[blockIdx.x] = tmp[t];
}

__global__ __launch_bounds__(1024) void scan_b(int* __restrict__ bsums, int nb) {
  __shared__ int tmp[1024];
  int t = threadIdx.x;
  int v = (t < nb) ? bsums[t] : 0;
  tmp[t] = v;
  __syncthreads();
  for (int off = 1; off < 1024; off <<= 1) {
    int a = tmp[t];
    if (t >= off) a += tmp[t - off];
    __syncthreads();
    tmp[t] = a;
    __syncthreads();
  }
  if (t < nb) bsums[t] = tmp[t];
}

__global__ __launch_bounds__(256) void scan_c(
    const int* __restrict__ counts, int* __restrict__ row_ptr,
    const int* __restrict__ bsums, int* __restrict__ cursor, int n) {
  int b = blockIdx.x;
  int idx = b * 256 + threadIdx.x;
  if (idx >= n) return;
  int off = (b > 0) ? bsums[b - 1] : 0;
  int incl = row_ptr[idx + 1] + off;
  row_ptr[idx + 1] = incl;
  cursor[idx] = incl - counts[idx];
  if (idx == 0) row_ptr[0] = 0;
}

__global__ __launch_bounds__(256) void scatter_edges(
    const int* __restrict__ erow, const int* __restrict__ ecol,
    const float* __restrict__ eval, int* __restrict__ cursor,
    int* __restrict__ scol, float* __restrict__ sval, int nnz) {
  int e = blockIdx.x * blockDim.x + threadIdx.x;
  if (e >= nnz) return;
  int r = erow[e];
  int pos = atomicAdd(&cursor[r], 1);
  scol[pos] = ecol[e];
  sval[pos] = eval[e];
}

// ---------------------------------------------------------------- SpMM (CSR, one wave per row)
__global__ __launch_bounds__(256) void spmm_csr(
    const int* __restrict__ row_ptr, const int* __restrict__ scol,
    const float* __restrict__ sval, const float* __restrict__ ego,
    float* __restrict__ side) {
  int row = blockIdx.x * 4 + (threadIdx.x >> 6);
  int lane = threadIdx.x & 63;
  if (row >= N_NODES_C) return;
  int s = row_ptr[row], e = row_ptr[row + 1];
  const float2* eg = reinterpret_cast<const float2*>(ego);
  float ax = 0.f, ay = 0.f;
  for (int base = s; base < e; base += 64) {
    int n = e - base;
    if (n > 64) n = 64;
    int c = 0;
    float v = 0.f;
    if (lane < n) {
      c = scol[base + lane];
      v = sval[base + lane];
    }
    for (int tt = 0; tt < n; ++tt) {
      int ct = __shfl(c, tt);
      float vt = __shfl(v, tt);
      float2 g = eg[(size_t)ct * 64 + lane];
      ax = fmaf(vt, g.x, ax);
      ay = fmaf(vt, g.y, ay);
    }
  }
  float2 o;
  o.x = ax;
  o.y = ay;
  reinterpret_cast<float2*>(side)[(size_t)row * 64 + lane] = o;
}

// ---------------------------------------------------------------- W prep: bf16 hi/lo split of [W1 | W2] rows
// whi/wlo layout: [layer][j 0..127][k 0..255], k<128 from fc1_w, k>=128 from fc2_w
__global__ __launch_bounds__(256) void prep_w(
    const float* __restrict__ fc1_w, const float* __restrict__ fc2_w,
    unsigned short* __restrict__ whi, unsigned short* __restrict__ wlo) {
  int idx = blockIdx.x * 256 + threadIdx.x;
  if (idx >= LAYERS_C * 128 * 256) return;
  int k = idx & 255;
  int j = (idx >> 8) & 127;
  int l = idx >> 15;
  float v = (k < 128) ? fc1_w[((size_t)l * 128 + j) * 128 + k]
                      : fc2_w[((size_t)l * 128 + j) * 128 + (k - 128)];
  unsigned short h = f2bf(v);
  whi[idx] = h;
  wlo[idx] = f2bf(v - bf2f(h));
}

// ---------------------------------------------------------------- fused dense layer (MFMA, split-bf16)
// Y[32 rows][128] = Z[32][256] @ Wcat^T, Z = [side | ego*side] cast hi/lo in LDS.
// Then ego' = leaky(Y + b1 + b2); ego = ego'; out += ego'/max(||row||,eps).
__global__ __launch_bounds__(256) void dense_mfma(
    const float* __restrict__ side, float* __restrict__ ego,
    const unsigned short* __restrict__ whi, const unsigned short* __restrict__ wlo,
    const float* __restrict__ b1, const float* __restrict__ b2,
    float* __restrict__ out) {
  __shared__ unsigned short A_hi[32 * 256];  // 16 KB, row stride 512 B, XOR-swizzled
  __shared__ unsigned short A_lo[32 * 256];  // 16 KB
  int t = threadIdx.x;
  int lane = t & 63;
  int w = t >> 6;  // wave 0..3 -> n-tiles {2w, 2w+1}
  int l15 = lane & 15;
  int lg = lane >> 4;
  int nb = blockIdx.x * 32;

  // ---- stage: load side/ego fp32, split to bf16 hi/lo, swizzled LDS write
#pragma unroll
  for (int i = 0; i < 4; ++i) {
    int f = i * 256 + t;  // float4 id in [0,1024)
    int row = f >> 5;     // 0..31
    int c4 = f & 31;      // 0..31
    size_t g = (size_t)(nb + row) * 32 + c4;
    float4 sv = reinterpret_cast<const float4*>(side)[g];
    float4 ev = reinterpret_cast<const float4*>(ego)[g];
    float s_[4] = {sv.x, sv.y, sv.z, sv.w};
    float e_[4] = {ev.x, ev.y, ev.z, ev.w};
    ushort4 sh, sl, ph, pl;
    unsigned short* shp = (unsigned short*)&sh;
    unsigned short* slp = (unsigned short*)&sl;
    unsigned short* php = (unsigned short*)&ph;
    unsigned short* plp = (unsigned short*)&pl;
#pragma unroll
    for (int j = 0; j < 4; ++j) {
      float x = s_[j];
      unsigned short h = f2bf(x);
      shp[j] = h;
      slp[j] = f2bf(x - bf2f(h));
      float p = s_[j] * e_[j];
      unsigned short hp = f2bf(p);
      php[j] = hp;
      plp[j] = f2bf(p - bf2f(hp));
    }
    int swz = (row & 7) << 4;
    int base_s = (row * 512 + c4 * 8) ^ swz;         // k = c4*4 (side half)
    int base_p = (row * 512 + 256 + c4 * 8) ^ swz;   // k = 128 + c4*4 (prod half)
    *(ushort4*)((char*)A_hi + base_s) = sh;
    *(ushort4*)((char*)A_lo + base_s) = sl;
    *(ushort4*)((char*)A_hi + base_p) = ph;
    *(ushort4*)((char*)A_lo + base_p) = pl;
  }

  // bias per owned output col
  float bias[2];
#pragma unroll
  for (int ntl = 0; ntl < 2; ++ntl) {
    int col = (w * 2 + ntl) * 16 + l15;
    bias[ntl] = b1[col] + b2[col];
  }

  __syncthreads();

  // ---- MFMA main loop: acc[mt][ntl], K = 256 in 8 steps of 32
  f32x4 zero = {0.f, 0.f, 0.f, 0.f};
  f32x4 acc[2][2] = {{zero, zero}, {zero, zero}};
#pragma unroll
  for (int kt = 0; kt < 8; ++kt) {
    int kb = kt * 64 + lg * 16;  // byte offset of this lane's k-slot within a row
    s16x8 a_hi[2], a_lo[2];
#pragma unroll
    for (int mt = 0; mt < 2; ++mt) {
      int row = mt * 16 + l15;
      int off = (row * 512 + kb) ^ ((row & 7) << 4);
      a_hi[mt] = *(const s16x8*)((const char*)A_hi + off);
      a_lo[mt] = *(const s16x8*)((const char*)A_lo + off);
    }
    s16x8 b_hi[2], b_lo[2];
#pragma unroll
    for (int ntl = 0; ntl < 2; ++ntl) {
      int j = (w * 2 + ntl) * 16 + l15;
      size_t woff = (size_t)j * 256 + kt * 32 + lg * 8;
      b_hi[ntl] = *(const s16x8*)(whi + woff);
      b_lo[ntl] = *(const s16x8*)(wlo + woff);
    }
#pragma unroll
    for (int mt = 0; mt < 2; ++mt)
#pragma unroll
      for (int ntl = 0; ntl < 2; ++ntl) {
        acc[mt][ntl] = MFMA16(a_hi[mt], b_hi[ntl], acc[mt][ntl]);
        acc[mt][ntl] = MFMA16(a_hi[mt], b_lo[ntl], acc[mt][ntl]);
        acc[mt][ntl] = MFMA16(a_lo[mt], b_hi[ntl], acc[mt][ntl]);
      }
  }

  __syncthreads();  // everyone done reading A before reuse as ylds

  // ---- epilogue: bias + leaky into swizzled fp32 y tile (reuse A_hi region)
  float* ylds = (float*)A_hi;  // 32 rows x 128 f32 = 16 KB, row stride 512 B
#pragma unroll
  for (int mt = 0; mt < 2; ++mt)
#pragma unroll
    for (int ntl = 0; ntl < 2; ++ntl) {
      int col = (w * 2 + ntl) * 16 + l15;
#pragma unroll
      for (int r = 0; r < 4; ++r) {
        int row = mt * 16 + lg * 4 + r;
        float a = acc[mt][ntl][r] + bias[ntl];
        float yv = (a >= 0.f) ? a : NEG_SLOPE_C * a;
        int off = (row * 512 + col * 4) ^ ((row & 7) << 4);
        *(float*)((char*)ylds + off) = yv;
      }
    }
  __syncthreads();

  // ---- store: row-norm (32-lane shfl reduce) + ego/out writeback, coalesced
#pragma unroll
  for (int i = 0; i < 4; ++i) {
    int f = i * 256 + t;
    int row = f >> 5;
    int c4 = f & 31;
    int off = (row * 512 + c4 * 16) ^ ((row & 7) << 4);
    float4 y = *(float4*)((char*)ylds + off);
    float ss = y.x * y.x + y.y * y.y + y.z * y.z + y.w * y.w;
#pragma unroll
    for (int m = 1; m <= 16; m <<= 1) ss += __shfl_xor(ss, m);
    float scale = 1.0f / fmaxf(sqrtf(ss), EPS_C);
    size_t g = (size_t)(nb + row) * 32 + c4;
    reinterpret_cast<float4*>(ego)[g] = y;
    float4 o = reinterpret_cast<float4*>(out)[g];
    o.x += y.x * scale;
    o.y += y.y * scale;
    o.z += y.z * scale;
    o.w += y.w * scale;
    reinterpret_cast<float4*>(out)[g] = o;
  }
}

// ---------------------------------------------------------------- launch
extern "C" void kernel_launch(void* const* d_in, const int* in_sizes, int n_in,
                              void* d_out, int out_size, void* d_ws,
                              size_t ws_size, hipStream_t stream) {
  const int* erow = (const int*)d_in[0];
  const int* ecol = (const int*)d_in[1];
  const float* eval = (const float*)d_in[2];
  const float* o_emb = (const float*)d_in[3];
  const int* u_id = (const int*)d_in[4];
  const float* user_emb = (const float*)d_in[5];
  const float* fc1_w = (const float*)d_in[6];
  const float* fc1_b = (const float*)d_in[7];
  const float* fc2_w = (const float*)d_in[8];
  const float* fc2_b = (const float*)d_in[9];
  float* out = (float*)d_out;
  int nnz = in_sizes[0];

  char* ws = (char*)d_ws;
  size_t off = 0;
  auto alloc = [&](size_t bytes) {
    void* p = ws + off;
    off += (bytes + 255) & ~(size_t)255;
    return p;
  };
  float* ego = (float*)alloc((size_t)N_NODES_C * EMBED_C * 4);
  float* side = (float*)alloc((size_t)N_NODES_C * EMBED_C * 4);
  int* scol = (int*)alloc((size_t)nnz * 4);
  float* sval = (float*)alloc((size_t)nnz * 4);
  int* row_ptr = (int*)alloc((size_t)(N_NODES_C + 1) * 4);
  int* counts = (int*)alloc((size_t)N_NODES_C * 4);
  int* cursor = (int*)alloc((size_t)N_NODES_C * 4);
  int* bsums = (int*)alloc(4096);
  unsigned short* whi = (unsigned short*)alloc((size_t)LAYERS_C * 128 * 256 * 2);
  unsigned short* wlo = (unsigned short*)alloc((size_t)LAYERS_C * 128 * 256 * 2);

  hipMemsetAsync(counts, 0, (size_t)N_NODES_C * 4, stream);
  init_ego_out<<<(N_NODES_C * 32 + 255) / 256, 256, 0, stream>>>(
      user_emb, u_id, o_emb, ego, out);
  count_edges<<<(nnz + 255) / 256, 256, 0, stream>>>(erow, counts, nnz);
  int nbs = (N_NODES_C + 255) / 256;
  scan_a<<<nbs, 256, 0, stream>>>(counts, row_ptr, bsums, N_NODES_C);
  scan_b<<<1, 1024, 0, stream>>>(bsums, nbs);
  scan_c<<<nbs, 256, 0, stream>>>(counts, row_ptr, bsums, cursor, N_NODES_C);
  scatter_edges<<<(nnz + 255) / 256, 256, 0, stream>>>(erow, ecol, eval, cursor,
                                                       scol, sval, nnz);
  prep_w<<<(LAYERS_C * 128 * 256 + 255) / 256, 256, 0, stream>>>(fc1_w, fc2_w,
                                                                 whi, wlo);
  for (int l = 0; l < LAYERS_C; ++l) {
    spmm_csr<<<(N_NODES_C + 3) / 4, 256, 0, stream>>>(row_ptr, scol, sval, ego,
                                                      side);
    dense_mfma<<<N_NODES_C / 32, 256, 0, stream>>>(
        side, ego, whi + (size_t)l * 32768, wlo + (size_t)l * 32768,
        fc1_b + l * EMBED_C, fc2_b + l * EMBED_C, out);
  }
}

// Round 3
// 2420.066 us; speedup vs baseline: 1.3783x; 1.0572x over previous
//
#include <hip/hip_runtime.h>

#define N_USERS_C 100000
#define N_OUTFITS_C 100000
#define N_NODES_C 200000
#define EMBED_C 128
#define LAYERS_C 3
#define NEG_SLOPE_C 0.01f
#define EPS_C 1e-12f

typedef float f32x4 __attribute__((ext_vector_type(4)));
typedef short s16x8 __attribute__((ext_vector_type(8)));
typedef __bf16 bf16x8 __attribute__((ext_vector_type(8)));

// ---- MFMA shim: works whether the builtin wants short8 or bf16x8 ----
template <typename T>
__device__ inline auto mfma_bf16_(T a, T b, f32x4 c, int)
    -> decltype(__builtin_amdgcn_mfma_f32_16x16x32_bf16(a, b, c, 0, 0, 0)) {
  return __builtin_amdgcn_mfma_f32_16x16x32_bf16(a, b, c, 0, 0, 0);
}
template <typename T>
__device__ inline f32x4 mfma_bf16_(T a, T b, f32x4 c, long) {
  union U { T s; bf16x8 b; };
  U ua; ua.s = a;
  U ub; ub.s = b;
  return __builtin_amdgcn_mfma_f32_16x16x32_bf16(ua.b, ub.b, c, 0, 0, 0);
}
__device__ inline f32x4 MFMA16(s16x8 a, s16x8 b, f32x4 c) {
  return mfma_bf16_(a, b, c, 0);
}

// ---- bf16 helpers (manual RNE) ----
__device__ inline unsigned short f2bf(float x) {
  unsigned u = __builtin_bit_cast(unsigned, x);
  u = (u + 0x7fffu + ((u >> 16) & 1u)) >> 16;
  return (unsigned short)u;
}
__device__ inline float bf2f(unsigned short h) {
  unsigned u = ((unsigned)h) << 16;
  return __builtin_bit_cast(float, u);
}

// ---------------------------------------------------------------- init
// out = ego (fp32); ego stored as bf16 hi/lo pair.
__global__ __launch_bounds__(256) void init_ego_out(
    const float* __restrict__ user_emb, const int* __restrict__ u_id,
    const float* __restrict__ o_emb, unsigned short* __restrict__ ego_hi,
    unsigned short* __restrict__ ego_lo, float* __restrict__ out) {
  int i4 = blockIdx.x * blockDim.x + threadIdx.x;  // float4 index
  if (i4 >= N_NODES_C * (EMBED_C / 4)) return;
  int r = i4 >> 5;  // row (EMBED/4 == 32)
  int c4 = i4 & 31;
  float4 v;
  if (r < N_USERS_C) {
    int src = u_id[r];
    v = reinterpret_cast<const float4*>(user_emb)[(size_t)src * 32 + c4];
  } else {
    v = reinterpret_cast<const float4*>(o_emb)[(size_t)(r - N_USERS_C) * 32 + c4];
  }
  reinterpret_cast<float4*>(out)[i4] = v;
  float vv[4] = {v.x, v.y, v.z, v.w};
  ushort4 h, l;
  unsigned short* hp = (unsigned short*)&h;
  unsigned short* lp = (unsigned short*)&l;
#pragma unroll
  for (int j = 0; j < 4; ++j) {
    unsigned short hh = f2bf(vv[j]);
    hp[j] = hh;
    lp[j] = f2bf(vv[j] - bf2f(hh));
  }
  reinterpret_cast<ushort4*>(ego_hi)[i4] = h;
  reinterpret_cast<ushort4*>(ego_lo)[i4] = l;
}

// ---------------------------------------------------------------- CSR build
__global__ __launch_bounds__(256) void count_edges(
    const int* __restrict__ erow, int* __restrict__ counts, int nnz) {
  int e = blockIdx.x * blockDim.x + threadIdx.x;
  if (e < nnz) atomicAdd(&counts[erow[e]], 1);
}

__global__ __launch_bounds__(256) void scan_a(
    const int* __restrict__ counts, int* __restrict__ row_ptr,
    int* __restrict__ bsums, int n) {
  __shared__ int tmp[256];
  int t = threadIdx.x;
  int idx = blockIdx.x * 256 + t;
  int v = (idx < n) ? counts[idx] : 0;
  tmp[t] = v;
  __syncthreads();
  for (int off = 1; off < 256; off <<= 1) {
    int a = tmp[t];
    if (t >= off) a += tmp[t - off];
    __syncthreads();
    tmp[t] = a;
    __syncthreads();
  }
  if (idx < n) row_ptr[idx + 1] = tmp[t];
  if (t == 255) bsums[blockIdx.x] = tmp[t];
}

__global__ __launch_bounds__(1024) void scan_b(int* __restrict__ bsums, int nb) {
  __shared__ int tmp[1024];
  int t = threadIdx.x;
  int v = (t < nb) ? bsums[t] : 0;
  tmp[t] = v;
  __syncthreads();
  for (int off = 1; off < 1024; off <<= 1) {
    int a = tmp[t];
    if (t >= off) a += tmp[t - off];
    __syncthreads();
    tmp[t] = a;
    __syncthreads();
  }
  if (t < nb) bsums[t] = tmp[t];
}

__global__ __launch_bounds__(256) void scan_c(
    const int* __restrict__ counts, int* __restrict__ row_ptr,
    const int* __restrict__ bsums, int* __restrict__ cursor, int n) {
  int b = blockIdx.x;
  int idx = b * 256 + threadIdx.x;
  if (idx >= n) return;
  int off = (b > 0) ? bsums[b - 1] : 0;
  int incl = row_ptr[idx + 1] + off;
  row_ptr[idx + 1] = incl;
  cursor[idx] = incl - counts[idx];
  if (idx == 0) row_ptr[0] = 0;
}

// packed (col, val-bits) -> single 8B random write per edge
__global__ __launch_bounds__(256) void scatter_edges(
    const int* __restrict__ erow, const int* __restrict__ ecol,
    const float* __restrict__ eval, int* __restrict__ cursor,
    int2* __restrict__ cv, int nnz) {
  int e = blockIdx.x * blockDim.x + threadIdx.x;
  if (e >= nnz) return;
  int r = erow[e];
  int pos = atomicAdd(&cursor[r], 1);
  int2 p;
  p.x = ecol[e];
  p.y = __builtin_bit_cast(int, eval[e]);
  cv[pos] = p;
}

// ---------------------------------------------------------------- SpMM (CSR, one wave per row, bf16 gather)
__global__ __launch_bounds__(256) void spmm_csr(
    const int* __restrict__ row_ptr, const int2* __restrict__ cv,
    const unsigned* __restrict__ ego_hi_u, float* __restrict__ side) {
  int row = blockIdx.x * 4 + (threadIdx.x >> 6);
  int lane = threadIdx.x & 63;
  if (row >= N_NODES_C) return;
  int s = row_ptr[row], e = row_ptr[row + 1];
  float ax = 0.f, ay = 0.f;
  for (int base = s; base < e; base += 64) {
    int n = e - base;
    if (n > 64) n = 64;
    int c = 0, vb = 0;
    if (lane < n) {
      int2 p = cv[base + lane];
      c = p.x;
      vb = p.y;
    }
    for (int tt = 0; tt < n; ++tt) {
      int ct = __shfl(c, tt);
      float vt = __builtin_bit_cast(float, __shfl(vb, tt));
      unsigned u = ego_hi_u[(size_t)ct * 64 + lane];  // 2 bf16 cols per lane
      float gx = __builtin_bit_cast(float, u << 16);
      float gy = __builtin_bit_cast(float, u & 0xffff0000u);
      ax = fmaf(vt, gx, ax);
      ay = fmaf(vt, gy, ay);
    }
  }
  float2 o;
  o.x = ax;
  o.y = ay;
  reinterpret_cast<float2*>(side)[(size_t)row * 64 + lane] = o;
}

// ---------------------------------------------------------------- W prep: bf16 hi/lo split of [W1 | W2] rows
__global__ __launch_bounds__(256) void prep_w(
    const float* __restrict__ fc1_w, const float* __restrict__ fc2_w,
    unsigned short* __restrict__ whi, unsigned short* __restrict__ wlo) {
  int idx = blockIdx.x * 256 + threadIdx.x;
  if (idx >= LAYERS_C * 128 * 256) return;
  int k = idx & 255;
  int j = (idx >> 8) & 127;
  int l = idx >> 15;
  float v = (k < 128) ? fc1_w[((size_t)l * 128 + j) * 128 + k]
                      : fc2_w[((size_t)l * 128 + j) * 128 + (k - 128)];
  unsigned short h = f2bf(v);
  whi[idx] = h;
  wlo[idx] = f2bf(v - bf2f(h));
}

// ---------------------------------------------------------------- fused dense layer (MFMA, split-bf16)
// Y[32][128] = Z[32][256] @ Wcat^T, Z = [side | ego*side]; ego = hi+lo.
// ego' = leaky(Y + b); ego_hi/lo <- split(ego'); out += ego'/max(||row||,eps).
__global__ __launch_bounds__(256) void dense_mfma(
    const float* __restrict__ side, unsigned short* __restrict__ ego_hi,
    unsigned short* __restrict__ ego_lo, const unsigned short* __restrict__ whi,
    const unsigned short* __restrict__ wlo, const float* __restrict__ b1,
    const float* __restrict__ b2, float* __restrict__ out) {
  __shared__ unsigned short A_hi[32 * 256];  // 16 KB, row stride 512 B, XOR-swizzled
  __shared__ unsigned short A_lo[32 * 256];  // 16 KB
  int t = threadIdx.x;
  int lane = t & 63;
  int w = t >> 6;  // wave 0..3 -> n-tiles {2w, 2w+1}
  int l15 = lane & 15;
  int lg = lane >> 4;
  int nb = blockIdx.x * 32;

  // ---- stage: side fp32 + ego(hi,lo) -> Z bf16 hi/lo, swizzled LDS write
#pragma unroll
  for (int i = 0; i < 4; ++i) {
    int f = i * 256 + t;  // float4-group id in [0,1024)
    int row = f >> 5;     // 0..31
    int c4 = f & 31;      // 0..31
    size_t g = (size_t)(nb + row) * 32 + c4;
    float4 sv = reinterpret_cast<const float4*>(side)[g];
    ushort4 hv = reinterpret_cast<const ushort4*>(ego_hi)[g];
    ushort4 lv = reinterpret_cast<const ushort4*>(ego_lo)[g];
    const unsigned short* hvp = (const unsigned short*)&hv;
    const unsigned short* lvp = (const unsigned short*)&lv;
    float s_[4] = {sv.x, sv.y, sv.z, sv.w};
    ushort4 sh, sl, ph, pl;
    unsigned short* shp = (unsigned short*)&sh;
    unsigned short* slp = (unsigned short*)&sl;
    unsigned short* php = (unsigned short*)&ph;
    unsigned short* plp = (unsigned short*)&pl;
#pragma unroll
    for (int j = 0; j < 4; ++j) {
      float x = s_[j];
      unsigned short h = f2bf(x);
      shp[j] = h;
      slp[j] = f2bf(x - bf2f(h));
      float e = bf2f(hvp[j]) + bf2f(lvp[j]);
      float p = x * e;
      unsigned short hp = f2bf(p);
      php[j] = hp;
      plp[j] = f2bf(p - bf2f(hp));
    }
    int swz = (row & 7) << 4;
    int base_s = (row * 512 + c4 * 8) ^ swz;        // k = c4*4 (side half)
    int base_p = (row * 512 + 256 + c4 * 8) ^ swz;  // k = 128 + c4*4 (prod half)
    *(ushort4*)((char*)A_hi + base_s) = sh;
    *(ushort4*)((char*)A_lo + base_s) = sl;
    *(ushort4*)((char*)A_hi + base_p) = ph;
    *(ushort4*)((char*)A_lo + base_p) = pl;
  }

  float bias[2];
#pragma unroll
  for (int ntl = 0; ntl < 2; ++ntl) {
    int col = (w * 2 + ntl) * 16 + l15;
    bias[ntl] = b1[col] + b2[col];
  }

  __syncthreads();

  // ---- MFMA main loop: acc[mt][ntl], K = 256 in 8 steps of 32
  f32x4 zero = {0.f, 0.f, 0.f, 0.f};
  f32x4 acc[2][2] = {{zero, zero}, {zero, zero}};
#pragma unroll
  for (int kt = 0; kt < 8; ++kt) {
    int kb = kt * 64 + lg * 16;  // byte offset of this lane's k-slot within a row
    s16x8 a_hi[2], a_lo[2];
#pragma unroll
    for (int mt = 0; mt < 2; ++mt) {
      int row = mt * 16 + l15;
      int off = (row * 512 + kb) ^ ((row & 7) << 4);
      a_hi[mt] = *(const s16x8*)((const char*)A_hi + off);
      a_lo[mt] = *(const s16x8*)((const char*)A_lo + off);
    }
    s16x8 b_hi[2], b_lo[2];
#pragma unroll
    for (int ntl = 0; ntl < 2; ++ntl) {
      int j = (w * 2 + ntl) * 16 + l15;
      size_t woff = (size_t)j * 256 + kt * 32 + lg * 8;
      b_hi[ntl] = *(const s16x8*)(whi + woff);
      b_lo[ntl] = *(const s16x8*)(wlo + woff);
    }
#pragma unroll
    for (int mt = 0; mt < 2; ++mt)
#pragma unroll
      for (int ntl = 0; ntl < 2; ++ntl) {
        acc[mt][ntl] = MFMA16(a_hi[mt], b_hi[ntl], acc[mt][ntl]);
        acc[mt][ntl] = MFMA16(a_hi[mt], b_lo[ntl], acc[mt][ntl]);
        acc[mt][ntl] = MFMA16(a_lo[mt], b_hi[ntl], acc[mt][ntl]);
      }
  }

  __syncthreads();  // everyone done reading A before reuse as ylds

  // ---- epilogue: bias + leaky into swizzled fp32 y tile (reuse A_hi region)
  float* ylds = (float*)A_hi;  // 32 rows x 128 f32, row stride 512 B
#pragma unroll
  for (int mt = 0; mt < 2; ++mt)
#pragma unroll
    for (int ntl = 0; ntl < 2; ++ntl) {
      int col = (w * 2 + ntl) * 16 + l15;
#pragma unroll
      for (int r = 0; r < 4; ++r) {
        int row = mt * 16 + lg * 4 + r;
        float a = acc[mt][ntl][r] + bias[ntl];
        float yv = (a >= 0.f) ? a : NEG_SLOPE_C * a;
        int off = (row * 512 + col * 4) ^ ((row & 7) << 4);
        *(float*)((char*)ylds + off) = yv;
      }
    }
  __syncthreads();

  // ---- store: row-norm (32-lane shfl reduce) + ego hi/lo + out writeback
#pragma unroll
  for (int i = 0; i < 4; ++i) {
    int f = i * 256 + t;
    int row = f >> 5;
    int c4 = f & 31;
    int off = (row * 512 + c4 * 16) ^ ((row & 7) << 4);
    float4 y = *(float4*)((char*)ylds + off);
    float ss = y.x * y.x + y.y * y.y + y.z * y.z + y.w * y.w;
#pragma unroll
    for (int m = 1; m <= 16; m <<= 1) ss += __shfl_xor(ss, m);
    float scale = 1.0f / fmaxf(sqrtf(ss), EPS_C);
    size_t g = (size_t)(nb + row) * 32 + c4;
    float yy[4] = {y.x, y.y, y.z, y.w};
    ushort4 h, l;
    unsigned short* hp = (unsigned short*)&h;
    unsigned short* lp = (unsigned short*)&l;
#pragma unroll
    for (int j = 0; j < 4; ++j) {
      unsigned short hh = f2bf(yy[j]);
      hp[j] = hh;
      lp[j] = f2bf(yy[j] - bf2f(hh));
    }
    reinterpret_cast<ushort4*>(ego_hi)[g] = h;
    reinterpret_cast<ushort4*>(ego_lo)[g] = l;
    float4 o = reinterpret_cast<float4*>(out)[g];
    o.x += y.x * scale;
    o.y += y.y * scale;
    o.z += y.z * scale;
    o.w += y.w * scale;
    reinterpret_cast<float4*>(out)[g] = o;
  }
}

// ---------------------------------------------------------------- launch
extern "C" void kernel_launch(void* const* d_in, const int* in_sizes, int n_in,
                              void* d_out, int out_size, void* d_ws,
                              size_t ws_size, hipStream_t stream) {
  const int* erow = (const int*)d_in[0];
  const int* ecol = (const int*)d_in[1];
  const float* eval = (const float*)d_in[2];
  const float* o_emb = (const float*)d_in[3];
  const int* u_id = (const int*)d_in[4];
  const float* user_emb = (const float*)d_in[5];
  const float* fc1_w = (const float*)d_in[6];
  const float* fc1_b = (const float*)d_in[7];
  const float* fc2_w = (const float*)d_in[8];
  const float* fc2_b = (const float*)d_in[9];
  float* out = (float*)d_out;
  int nnz = in_sizes[0];

  char* ws = (char*)d_ws;
  size_t off = 0;
  auto alloc = [&](size_t bytes) {
    void* p = ws + off;
    off += (bytes + 255) & ~(size_t)255;
    return p;
  };
  unsigned short* ego_hi = (unsigned short*)alloc((size_t)N_NODES_C * EMBED_C * 2);
  unsigned short* ego_lo = (unsigned short*)alloc((size_t)N_NODES_C * EMBED_C * 2);
  float* side = (float*)alloc((size_t)N_NODES_C * EMBED_C * 4);
  int2* cv = (int2*)alloc((size_t)nnz * 8);
  int* row_ptr = (int*)alloc((size_t)(N_NODES_C + 1) * 4);
  int* counts = (int*)alloc((size_t)N_NODES_C * 4);
  int* cursor = (int*)alloc((size_t)N_NODES_C * 4);
  int* bsums = (int*)alloc(4096);
  unsigned short* whi = (unsigned short*)alloc((size_t)LAYERS_C * 128 * 256 * 2);
  unsigned short* wlo = (unsigned short*)alloc((size_t)LAYERS_C * 128 * 256 * 2);

  hipMemsetAsync(counts, 0, (size_t)N_NODES_C * 4, stream);
  init_ego_out<<<(N_NODES_C * 32 + 255) / 256, 256, 0, stream>>>(
      user_emb, u_id, o_emb, ego_hi, ego_lo, out);
  count_edges<<<(nnz + 255) / 256, 256, 0, stream>>>(erow, counts, nnz);
  int nbs = (N_NODES_C + 255) / 256;
  scan_a<<<nbs, 256, 0, stream>>>(counts, row_ptr, bsums, N_NODES_C);
  scan_b<<<1, 1024, 0, stream>>>(bsums, nbs);
  scan_c<<<nbs, 256, 0, stream>>>(counts, row_ptr, bsums, cursor, N_NODES_C);
  scatter_edges<<<(nnz + 255) / 256, 256, 0, stream>>>(erow, ecol, eval, cursor,
                                                       cv, nnz);
  prep_w<<<(LAYERS_C * 128 * 256 + 255) / 256, 256, 0, stream>>>(fc1_w, fc2_w,
                                                                 whi, wlo);
  for (int l = 0; l < LAYERS_C; ++l) {
    spmm_csr<<<(N_NODES_C + 3) / 4, 256, 0, stream>>>(
        row_ptr, cv, (const unsigned*)ego_hi, side);
    dense_mfma<<<N_NODES_C / 32, 256, 0, stream>>>(
        side, ego_hi, ego_lo, whi + (size_t)l * 32768, wlo + (size_t)l * 32768,
        fc1_b + l * EMBED_C, fc2_b + l * EMBED_C, out);
  }
}

// Round 4
// 1972.758 us; speedup vs baseline: 1.6909x; 1.2267x over previous
//
#include <hip/hip_runtime.h>

#define N_USERS_C 100000
#define N_OUTFITS_C 100000
#define N_NODES_C 200000
#define EMBED_C 128
#define LAYERS_C 3
#define NEG_SLOPE_C 0.01f
#define EPS_C 1e-12f

#define NBUCK 25       // coarse buckets: row >> 13 (8192 rows each)
#define BSHIFT 13
#define BCAP 300000    // per-bucket staging capacity (mean 262144, 12+ sigma)
#define A2_CHUNKS 24   // chunks per bucket in scatter_stage

typedef float f32x4 __attribute__((ext_vector_type(4)));
typedef short s16x8 __attribute__((ext_vector_type(8)));
typedef __bf16 bf16x8 __attribute__((ext_vector_type(8)));

// ---- MFMA shim: works whether the builtin wants short8 or bf16x8 ----
template <typename T>
__device__ inline auto mfma_bf16_(T a, T b, f32x4 c, int)
    -> decltype(__builtin_amdgcn_mfma_f32_16x16x32_bf16(a, b, c, 0, 0, 0)) {
  return __builtin_amdgcn_mfma_f32_16x16x32_bf16(a, b, c, 0, 0, 0);
}
template <typename T>
__device__ inline f32x4 mfma_bf16_(T a, T b, f32x4 c, long) {
  union U { T s; bf16x8 b; };
  U ua; ua.s = a;
  U ub; ub.s = b;
  return __builtin_amdgcn_mfma_f32_16x16x32_bf16(ua.b, ub.b, c, 0, 0, 0);
}
__device__ inline f32x4 MFMA16(s16x8 a, s16x8 b, f32x4 c) {
  return mfma_bf16_(a, b, c, 0);
}

// ---- bf16 helpers (manual RNE) ----
__device__ inline unsigned short f2bf(float x) {
  unsigned u = __builtin_bit_cast(unsigned, x);
  u = (u + 0x7fffu + ((u >> 16) & 1u)) >> 16;
  return (unsigned short)u;
}
__device__ inline float bf2f(unsigned short h) {
  unsigned u = ((unsigned)h) << 16;
  return __builtin_bit_cast(float, u);
}

// ---------------------------------------------------------------- init
__global__ __launch_bounds__(256) void init_ego_out(
    const float* __restrict__ user_emb, const int* __restrict__ u_id,
    const float* __restrict__ o_emb, unsigned short* __restrict__ ego_hi,
    unsigned short* __restrict__ ego_lo, float* __restrict__ out) {
  int i4 = blockIdx.x * blockDim.x + threadIdx.x;  // float4 index
  if (i4 >= N_NODES_C * (EMBED_C / 4)) return;
  int r = i4 >> 5;
  int c4 = i4 & 31;
  float4 v;
  if (r < N_USERS_C) {
    int src = u_id[r];
    v = reinterpret_cast<const float4*>(user_emb)[(size_t)src * 32 + c4];
  } else {
    v = reinterpret_cast<const float4*>(o_emb)[(size_t)(r - N_USERS_C) * 32 + c4];
  }
  reinterpret_cast<float4*>(out)[i4] = v;
  float vv[4] = {v.x, v.y, v.z, v.w};
  ushort4 h, l;
  unsigned short* hp = (unsigned short*)&h;
  unsigned short* lp = (unsigned short*)&l;
#pragma unroll
  for (int j = 0; j < 4; ++j) {
    unsigned short hh = f2bf(vv[j]);
    hp[j] = hh;
    lp[j] = f2bf(vv[j] - bf2f(hh));
  }
  reinterpret_cast<ushort4*>(ego_hi)[i4] = h;
  reinterpret_cast<ushort4*>(ego_lo)[i4] = l;
}

// ---------------------------------------------------------------- gcur init
__global__ void init_gcur(int* __restrict__ gcur) {
  int t = threadIdx.x;
  if (t < NBUCK) gcur[t] = t * BCAP;
}

// ---------------------------------------------------------------- A1: coarse partition (+ row histogram)
// tile = 2048 edges per block; LDS reorder -> bucket-contiguous coalesced flush
__global__ __launch_bounds__(256) void partition_edges(
    const int* __restrict__ erow, const int* __restrict__ ecol,
    const float* __restrict__ eval, int* __restrict__ counts,
    int* __restrict__ gcur, int2* __restrict__ stage, int nnz) {
  __shared__ int2 scratch[2048];
  __shared__ unsigned char sbid[2048];
  __shared__ int hist[NBUCK], lbase[NBUCK], gbase[NBUCK];
  int t = threadIdx.x;
  int base = blockIdx.x * 2048;
  if (base + 2048 > nnz) return;  // nnz is an exact multiple of 2048 (6.4M)
  if (t < NBUCK) hist[t] = 0;
  __syncthreads();
  int rowv[8], colv[8], bb[8], rk[8], vv[8];
#pragma unroll
  for (int r = 0; r < 8; ++r) {
    int e = base + t + r * 256;
    rowv[r] = erow[e];
    colv[r] = ecol[e];
    vv[r] = __builtin_bit_cast(int, eval[e]);
  }
#pragma unroll
  for (int r = 0; r < 8; ++r) {
    bb[r] = rowv[r] >> BSHIFT;
    rk[r] = atomicAdd(&hist[bb[r]], 1);
    atomicAdd(&counts[rowv[r]], 1);
  }
  __syncthreads();
  // exclusive scan of hist (25 entries) in wave 0 + global cursor grab
  if (t < 64) {
    int v = (t < NBUCK) ? hist[t] : 0;
    int s = v;
#pragma unroll
    for (int off = 1; off < 32; off <<= 1) {
      int n = __shfl_up(s, off);
      if (t >= off) s += n;
    }
    if (t < NBUCK) lbase[t] = s - v;
  }
  __syncthreads();
  if (t < NBUCK) gbase[t] = atomicAdd(&gcur[t], hist[t]);
  __syncthreads();
#pragma unroll
  for (int r = 0; r < 8; ++r) {
    int slot = lbase[bb[r]] + rk[r];
    int2 p;
    p.x = (int)(((unsigned)(rowv[r] & ((1 << BSHIFT) - 1)) << 18) |
                (unsigned)colv[r]);
    p.y = vv[r];
    scratch[slot] = p;
    sbid[slot] = (unsigned char)bb[r];
  }
  __syncthreads();
#pragma unroll
  for (int q = 0; q < 8; ++q) {
    int i = t + q * 256;
    int b = sbid[i];
    stage[(size_t)gbase[b] + (i - lbase[b])] = scratch[i];
  }
}

// ---------------------------------------------------------------- CSR scans (row_ptr, cursor)
__global__ __launch_bounds__(256) void scan_a(
    const int* __restrict__ counts, int* __restrict__ row_ptr,
    int* __restrict__ bsums, int n) {
  __shared__ int tmp[256];
  int t = threadIdx.x;
  int idx = blockIdx.x * 256 + t;
  int v = (idx < n) ? counts[idx] : 0;
  tmp[t] = v;
  __syncthreads();
  for (int off = 1; off < 256; off <<= 1) {
    int a = tmp[t];
    if (t >= off) a += tmp[t - off];
    __syncthreads();
    tmp[t] = a;
    __syncthreads();
  }
  if (idx < n) row_ptr[idx + 1] = tmp[t];
  if (t == 255) bsums[blockIdx.x] = tmp[t];
}

__global__ __launch_bounds__(1024) void scan_b(int* __restrict__ bsums, int nb) {
  __shared__ int tmp[1024];
  int t = threadIdx.x;
  int v = (t < nb) ? bsums[t] : 0;
  tmp[t] = v;
  __syncthreads();
  for (int off = 1; off < 1024; off <<= 1) {
    int a = tmp[t];
    if (t >= off) a += tmp[t - off];
    __syncthreads();
    tmp[t] = a;
    __syncthreads();
  }
  if (t < nb) bsums[t] = tmp[t];
}

__global__ __launch_bounds__(256) void scan_c(
    const int* __restrict__ counts, int* __restrict__ row_ptr,
    const int* __restrict__ bsums, int* __restrict__ cursor, int n) {
  int b = blockIdx.x;
  int idx = b * 256 + threadIdx.x;
  if (idx >= n) return;
  int off = (b > 0) ? bsums[b - 1] : 0;
  int incl = row_ptr[idx + 1] + off;
  row_ptr[idx + 1] = incl;
  cursor[idx] = incl - counts[idx];
  if (idx == 0) row_ptr[0] = 0;
}

// ---------------------------------------------------------------- A2: bucket -> exact CSR (L2-local random writes)
// blockIdx chosen so all chunks of a bucket share an XCD: id%8 == b%8.
__global__ __launch_bounds__(256) void scatter_stage(
    const int2* __restrict__ stage, const int* __restrict__ gcur,
    int* __restrict__ cursor, int2* __restrict__ cv) {
  int id = blockIdx.x;
  int x = id & 7;
  int q = id >> 3;             // 0 .. 4*A2_CHUNKS-1
  int bhi = q / A2_CHUNKS;     // 0..3
  int j = q % A2_CHUNKS;
  int b = bhi * 8 + x;
  if (b >= NBUCK) return;
  int cnt = gcur[b] - b * BCAP;
  int s0 = (int)(((long)cnt * j) / A2_CHUNKS);
  int s1 = (int)(((long)cnt * (j + 1)) / A2_CHUNKS);
  const int2* src = stage + (size_t)b * BCAP;
  int rbase = b << BSHIFT;
  for (int i = s0 + threadIdx.x; i < s1; i += 256) {
    int2 p = src[i];
    int row = rbase + (int)((unsigned)p.x >> 18);
    int col = p.x & 0x3FFFF;
    int pos = atomicAdd(&cursor[row], 1);
    int2 o;
    o.x = col;
    o.y = p.y;
    cv[pos] = o;
  }
}

// ---------------------------------------------------------------- SpMM (CSR, wave/row, bf16 gather, x8 unroll)
__global__ __launch_bounds__(256) void spmm_csr(
    const int* __restrict__ row_ptr, const int2* __restrict__ cv,
    const unsigned* __restrict__ ego_hi_u, float* __restrict__ side) {
  int row = blockIdx.x * 4 + (threadIdx.x >> 6);
  int lane = threadIdx.x & 63;
  if (row >= N_NODES_C) return;
  int s = row_ptr[row], e = row_ptr[row + 1];
  float ax = 0.f, ay = 0.f;
  for (int base = s; base < e; base += 64) {
    int n = e - base;
    if (n > 64) n = 64;
    int c = 0, vb = 0;
    if (lane < n) {
      int2 p = cv[base + lane];
      c = p.x;
      vb = p.y;
    }
    int tt = 0;
    for (; tt + 8 <= n; tt += 8) {
      unsigned u[8];
      float vt[8];
#pragma unroll
      for (int q2 = 0; q2 < 8; ++q2) {
        int ct = __shfl(c, tt + q2);
        vt[q2] = __builtin_bit_cast(float, __shfl(vb, tt + q2));
        u[q2] = ego_hi_u[(size_t)ct * 64 + lane];
      }
#pragma unroll
      for (int q2 = 0; q2 < 8; ++q2) {
        ax = fmaf(vt[q2], __builtin_bit_cast(float, u[q2] << 16), ax);
        ay = fmaf(vt[q2], __builtin_bit_cast(float, u[q2] & 0xffff0000u), ay);
      }
    }
    for (; tt < n; ++tt) {
      int ct = __shfl(c, tt);
      float vtt = __builtin_bit_cast(float, __shfl(vb, tt));
      unsigned uu = ego_hi_u[(size_t)ct * 64 + lane];
      ax = fmaf(vtt, __builtin_bit_cast(float, uu << 16), ax);
      ay = fmaf(vtt, __builtin_bit_cast(float, uu & 0xffff0000u), ay);
    }
  }
  float2 o;
  o.x = ax;
  o.y = ay;
  reinterpret_cast<float2*>(side)[(size_t)row * 64 + lane] = o;
}

// ---------------------------------------------------------------- W prep: bf16 hi/lo split of [W1 | W2]
__global__ __launch_bounds__(256) void prep_w(
    const float* __restrict__ fc1_w, const float* __restrict__ fc2_w,
    unsigned short* __restrict__ whi, unsigned short* __restrict__ wlo) {
  int idx = blockIdx.x * 256 + threadIdx.x;
  if (idx >= LAYERS_C * 128 * 256) return;
  int k = idx & 255;
  int j = (idx >> 8) & 127;
  int l = idx >> 15;
  float v = (k < 128) ? fc1_w[((size_t)l * 128 + j) * 128 + k]
                      : fc2_w[((size_t)l * 128 + j) * 128 + (k - 128)];
  unsigned short h = f2bf(v);
  whi[idx] = h;
  wlo[idx] = f2bf(v - bf2f(h));
}

// ---------------------------------------------------------------- fused dense layer (MFMA, split-bf16)
__global__ __launch_bounds__(256) void dense_mfma(
    const float* __restrict__ side, unsigned short* __restrict__ ego_hi,
    unsigned short* __restrict__ ego_lo, const unsigned short* __restrict__ whi,
    const unsigned short* __restrict__ wlo, const float* __restrict__ b1,
    const float* __restrict__ b2, float* __restrict__ out) {
  __shared__ unsigned short A_hi[32 * 256];
  __shared__ unsigned short A_lo[32 * 256];
  int t = threadIdx.x;
  int lane = t & 63;
  int w = t >> 6;
  int l15 = lane & 15;
  int lg = lane >> 4;
  int nb = blockIdx.x * 32;

#pragma unroll
  for (int i = 0; i < 4; ++i) {
    int f = i * 256 + t;
    int row = f >> 5;
    int c4 = f & 31;
    size_t g = (size_t)(nb + row) * 32 + c4;
    float4 sv = reinterpret_cast<const float4*>(side)[g];
    ushort4 hv = reinterpret_cast<const ushort4*>(ego_hi)[g];
    ushort4 lv = reinterpret_cast<const ushort4*>(ego_lo)[g];
    const unsigned short* hvp = (const unsigned short*)&hv;
    const unsigned short* lvp = (const unsigned short*)&lv;
    float s_[4] = {sv.x, sv.y, sv.z, sv.w};
    ushort4 sh, sl, ph, pl;
    unsigned short* shp = (unsigned short*)&sh;
    unsigned short* slp = (unsigned short*)&sl;
    unsigned short* php = (unsigned short*)&ph;
    unsigned short* plp = (unsigned short*)&pl;
#pragma unroll
    for (int j = 0; j < 4; ++j) {
      float x = s_[j];
      unsigned short h = f2bf(x);
      shp[j] = h;
      slp[j] = f2bf(x - bf2f(h));
      float e = bf2f(hvp[j]) + bf2f(lvp[j]);
      float p = x * e;
      unsigned short hp = f2bf(p);
      php[j] = hp;
      plp[j] = f2bf(p - bf2f(hp));
    }
    int swz = (row & 7) << 4;
    int base_s = (row * 512 + c4 * 8) ^ swz;
    int base_p = (row * 512 + 256 + c4 * 8) ^ swz;
    *(ushort4*)((char*)A_hi + base_s) = sh;
    *(ushort4*)((char*)A_lo + base_s) = sl;
    *(ushort4*)((char*)A_hi + base_p) = ph;
    *(ushort4*)((char*)A_lo + base_p) = pl;
  }

  float bias[2];
#pragma unroll
  for (int ntl = 0; ntl < 2; ++ntl) {
    int col = (w * 2 + ntl) * 16 + l15;
    bias[ntl] = b1[col] + b2[col];
  }

  __syncthreads();

  f32x4 zero = {0.f, 0.f, 0.f, 0.f};
  f32x4 acc[2][2] = {{zero, zero}, {zero, zero}};
#pragma unroll
  for (int kt = 0; kt < 8; ++kt) {
    int kb = kt * 64 + lg * 16;
    s16x8 a_hi[2], a_lo[2];
#pragma unroll
    for (int mt = 0; mt < 2; ++mt) {
      int row = mt * 16 + l15;
      int off = (row * 512 + kb) ^ ((row & 7) << 4);
      a_hi[mt] = *(const s16x8*)((const char*)A_hi + off);
      a_lo[mt] = *(const s16x8*)((const char*)A_lo + off);
    }
    s16x8 b_hi[2], b_lo[2];
#pragma unroll
    for (int ntl = 0; ntl < 2; ++ntl) {
      int j = (w * 2 + ntl) * 16 + l15;
      size_t woff = (size_t)j * 256 + kt * 32 + lg * 8;
      b_hi[ntl] = *(const s16x8*)(whi + woff);
      b_lo[ntl] = *(const s16x8*)(wlo + woff);
    }
#pragma unroll
    for (int mt = 0; mt < 2; ++mt)
#pragma unroll
      for (int ntl = 0; ntl < 2; ++ntl) {
        acc[mt][ntl] = MFMA16(a_hi[mt], b_hi[ntl], acc[mt][ntl]);
        acc[mt][ntl] = MFMA16(a_hi[mt], b_lo[ntl], acc[mt][ntl]);
        acc[mt][ntl] = MFMA16(a_lo[mt], b_hi[ntl], acc[mt][ntl]);
      }
  }

  __syncthreads();

  float* ylds = (float*)A_hi;
#pragma unroll
  for (int mt = 0; mt < 2; ++mt)
#pragma unroll
    for (int ntl = 0; ntl < 2; ++ntl) {
      int col = (w * 2 + ntl) * 16 + l15;
#pragma unroll
      for (int r = 0; r < 4; ++r) {
        int row = mt * 16 + lg * 4 + r;
        float a = acc[mt][ntl][r] + bias[ntl];
        float yv = (a >= 0.f) ? a : NEG_SLOPE_C * a;
        int off = (row * 512 + col * 4) ^ ((row & 7) << 4);
        *(float*)((char*)ylds + off) = yv;
      }
    }
  __syncthreads();

#pragma unroll
  for (int i = 0; i < 4; ++i) {
    int f = i * 256 + t;
    int row = f >> 5;
    int c4 = f & 31;
    int off = (row * 512 + c4 * 16) ^ ((row & 7) << 4);
    float4 y = *(float4*)((char*)ylds + off);
    float ss = y.x * y.x + y.y * y.y + y.z * y.z + y.w * y.w;
#pragma unroll
    for (int m = 1; m <= 16; m <<= 1) ss += __shfl_xor(ss, m);
    float scale = 1.0f / fmaxf(sqrtf(ss), EPS_C);
    size_t g = (size_t)(nb + row) * 32 + c4;
    float yy[4] = {y.x, y.y, y.z, y.w};
    ushort4 h, l;
    unsigned short* hp = (unsigned short*)&h;
    unsigned short* lp = (unsigned short*)&l;
#pragma unroll
    for (int j = 0; j < 4; ++j) {
      unsigned short hh = f2bf(yy[j]);
      hp[j] = hh;
      lp[j] = f2bf(yy[j] - bf2f(hh));
    }
    reinterpret_cast<ushort4*>(ego_hi)[g] = h;
    reinterpret_cast<ushort4*>(ego_lo)[g] = l;
    float4 o = reinterpret_cast<float4*>(out)[g];
    o.x += y.x * scale;
    o.y += y.y * scale;
    o.z += y.z * scale;
    o.w += y.w * scale;
    reinterpret_cast<float4*>(out)[g] = o;
  }
}

// ---------------------------------------------------------------- launch
extern "C" void kernel_launch(void* const* d_in, const int* in_sizes, int n_in,
                              void* d_out, int out_size, void* d_ws,
                              size_t ws_size, hipStream_t stream) {
  const int* erow = (const int*)d_in[0];
  const int* ecol = (const int*)d_in[1];
  const float* eval = (const float*)d_in[2];
  const float* o_emb = (const float*)d_in[3];
  const int* u_id = (const int*)d_in[4];
  const float* user_emb = (const float*)d_in[5];
  const float* fc1_w = (const float*)d_in[6];
  const float* fc1_b = (const float*)d_in[7];
  const float* fc2_w = (const float*)d_in[8];
  const float* fc2_b = (const float*)d_in[9];
  float* out = (float*)d_out;
  int nnz = in_sizes[0];

  char* ws = (char*)d_ws;
  size_t off = 0;
  auto alloc = [&](size_t bytes) {
    void* p = ws + off;
    off += (bytes + 255) & ~(size_t)255;
    return p;
  };
  unsigned short* ego_hi = (unsigned short*)alloc((size_t)N_NODES_C * EMBED_C * 2);
  unsigned short* ego_lo = (unsigned short*)alloc((size_t)N_NODES_C * EMBED_C * 2);
  float* side = (float*)alloc((size_t)N_NODES_C * EMBED_C * 4);  // >= 60MB, aliased as stage
  int2* cv = (int2*)alloc((size_t)nnz * 8);
  int* row_ptr = (int*)alloc((size_t)(N_NODES_C + 1) * 4);
  int* counts = (int*)alloc((size_t)N_NODES_C * 4);
  int* cursor = (int*)alloc((size_t)N_NODES_C * 4);
  int* bsums = (int*)alloc(4096);
  unsigned short* whi = (unsigned short*)alloc((size_t)LAYERS_C * 128 * 256 * 2);
  unsigned short* wlo = (unsigned short*)alloc((size_t)LAYERS_C * 128 * 256 * 2);
  int* gcur = (int*)alloc(256);
  int2* stage = (int2*)side;  // alias: stage dead before spmm writes side

  hipMemsetAsync(counts, 0, (size_t)N_NODES_C * 4, stream);
  init_gcur<<<1, 64, 0, stream>>>(gcur);
  init_ego_out<<<(N_NODES_C * 32 + 255) / 256, 256, 0, stream>>>(
      user_emb, u_id, o_emb, ego_hi, ego_lo, out);
  partition_edges<<<nnz / 2048, 256, 0, stream>>>(erow, ecol, eval, counts,
                                                  gcur, stage, nnz);
  int nbs = (N_NODES_C + 255) / 256;
  scan_a<<<nbs, 256, 0, stream>>>(counts, row_ptr, bsums, N_NODES_C);
  scan_b<<<1, 1024, 0, stream>>>(bsums, nbs);
  scan_c<<<nbs, 256, 0, stream>>>(counts, row_ptr, bsums, cursor, N_NODES_C);
  scatter_stage<<<8 * 4 * A2_CHUNKS, 256, 0, stream>>>(stage, gcur, cursor, cv);
  prep_w<<<(LAYERS_C * 128 * 256 + 255) / 256, 256, 0, stream>>>(fc1_w, fc2_w,
                                                                 whi, wlo);
  for (int l = 0; l < LAYERS_C; ++l) {
    spmm_csr<<<(N_NODES_C + 3) / 4, 256, 0, stream>>>(
        row_ptr, cv, (const unsigned*)ego_hi, side);
    dense_mfma<<<N_NODES_C / 32, 256, 0, stream>>>(
        side, ego_hi, ego_lo, whi + (size_t)l * 32768, wlo + (size_t)l * 32768,
        fc1_b + l * EMBED_C, fc2_b + l * EMBED_C, out);
  }
}